// Round 1
// baseline (2348.501 us; speedup 1.0000x reference)
//
#include <hip/hip_runtime.h>

// Sparse 3x3x3 conv, gather formulation.
// Coordinates are in [0,127] (inputs) / probes in [0,129] (bounds-checked).
// Workspace layout:
//   [0, 8MB)              : int32 table[1<<21], cell -> input row (-1 empty)
//   [8MB, 8MB + N*32*4)   : float featcopy[N][32], duplicate rows pre-summed

#define CELLS (1 << 21)
#define TABLE_BYTES (CELLS * 4)

__global__ void init_table_k(int4* table) {
    int i = blockIdx.x * blockDim.x + threadIdx.x;
    if (i < (CELLS / 4)) table[i] = make_int4(-1, -1, -1, -1);
}

// Copy features to workspace (float4) and claim cells via CAS.
__global__ void stage_k(const float4* __restrict__ feat4, const int* __restrict__ ipos,
                        float4* __restrict__ fc4, int* __restrict__ table, int N) {
    int t = blockIdx.x * blockDim.x + threadIdx.x;
    int n = t >> 3;
    if (n >= N) return;
    int lane = t & 7;
    fc4[n * 8 + lane] = feat4[n * 8 + lane];
    if (lane == 0) {
        int x = ipos[3 * n], y = ipos[3 * n + 1], z = ipos[3 * n + 2];
        atomicCAS(&table[(x << 14) | (y << 7) | z], -1, n);
    }
}

// Points that lost the CAS add their features into the owner's featcopy row.
__global__ void dups_k(const float* __restrict__ feat, const int* __restrict__ ipos,
                       float* __restrict__ fc, const int* __restrict__ table, int N) {
    int n = blockIdx.x * blockDim.x + threadIdx.x;
    if (n >= N) return;
    int x = ipos[3 * n], y = ipos[3 * n + 1], z = ipos[3 * n + 2];
    int owner = table[(x << 14) | (y << 7) | z];
    if (owner != n) {
        for (int c = 0; c < 32; c++)
            atomicAdd(&fc[owner * 32 + c], feat[n * 32 + c]);
    }
}

// Main gather: 32 threads per output row; thread f computes out[q, f].
__global__ void gather_k(const int* __restrict__ opos, const int* __restrict__ table,
                         const float* __restrict__ fc, const float* __restrict__ W,
                         float* __restrict__ out, int M) {
    int gid = blockIdx.x * blockDim.x + threadIdx.x;
    int q = gid >> 5;
    int f = gid & 31;
    if (q >= M) return;
    int ox = opos[3 * q], oy = opos[3 * q + 1], oz = opos[3 * q + 2];
    float acc = 0.f;
    #pragma unroll
    for (int k = 0; k < 27; k++) {
        const int dx = k / 9, dy = (k / 3) % 3, dz = k % 3;
        int px = ox + dx, py = oy + dy, pz = oz + dz;
        if (px > 127 || py > 127 || pz > 127) continue;
        int j = table[(px << 14) | (py << 7) | pz];
        if (j < 0) continue;
        const float4* fr = (const float4*)(fc + j * 32);
        const float* wk = W + k * 1024 + f;
        #pragma unroll
        for (int c = 0; c < 32; c += 4) {
            float4 x4 = fr[c >> 2];  // wave-broadcast (same addr per half-wave)
            acc += x4.x * wk[(c + 0) * 32];
            acc += x4.y * wk[(c + 1) * 32];
            acc += x4.z * wk[(c + 2) * 32];
            acc += x4.w * wk[(c + 3) * 32];
        }
    }
    out[q * 32 + f] = acc;
}

extern "C" void kernel_launch(void* const* d_in, const int* in_sizes, int n_in,
                              void* d_out, int out_size, void* d_ws, size_t ws_size,
                              hipStream_t stream) {
    const float* features = (const float*)d_in[0];
    const int* in_pos     = (const int*)d_in[1];
    const int* out_pos    = (const int*)d_in[2];
    const float* W        = (const float*)d_in[3];
    float* out            = (float*)d_out;

    const int N = in_sizes[1] / 3;
    const int M = in_sizes[2] / 3;

    int* table  = (int*)d_ws;
    float* fc   = (float*)((char*)d_ws + TABLE_BYTES);

    // 1. table = -1
    init_table_k<<<(CELLS / 4 + 255) / 256, 256, 0, stream>>>((int4*)table);
    // 2. copy features, CAS-claim cells
    stage_k<<<(N * 8 + 255) / 256, 256, 0, stream>>>(
        (const float4*)features, in_pos, (float4*)fc, table, N);
    // 3. fold duplicate positions into owner rows
    dups_k<<<(N + 255) / 256, 256, 0, stream>>>(features, in_pos, fc, table, N);
    // 4. gather conv
    gather_k<<<(M * 32 + 255) / 256, 256, 0, stream>>>(out_pos, table, fc, W, out, M);
}

// Round 2
// 1755.387 us; speedup vs baseline: 1.3379x; 1.3379x over previous
//
#include <hip/hip_runtime.h>

// Sparse 3x3x3 conv — scatter-record formulation.
// Out set == in_pos + {-2,-1,0}^3 (dedup'd), so every (input n, tap k) with
// in_pos[n]-d_k >= 0 maps to exactly one output row: no probe misses.
//
// Pipeline:
//   K1 rtable:  cell -> out-row q   (only out-set cells ever read; no init needed)
//   K2 count:   counts[q] += 1 per valid (n,k)          [4M int atomics]
//   K3 bases:   base[q] = atomicAdd(total, counts[q]); counts[q] = 0
//   K4 fill:    records[base[q] + counts[q]++] = n | (k<<18)
//   K5 gather:  out[q,f] = sum over records of  feat[n,:] . W[k,:,f]
//
// Workspace: rtable 8MB | counts M*4 | total 4B | base M*4 | records 27N*4

#define CELLS (1 << 21)

__global__ void rtable_k(const int* __restrict__ opos, int* __restrict__ rtable, int M) {
    int q = blockIdx.x * blockDim.x + threadIdx.x;
    if (q >= M) return;
    int x = opos[3 * q], y = opos[3 * q + 1], z = opos[3 * q + 2];
    rtable[(x << 14) | (y << 7) | z] = q;
}

__global__ void count_k(const int* __restrict__ ipos, const int* __restrict__ rtable,
                        int* __restrict__ counts, int N) {
    int gid = blockIdx.x * blockDim.x + threadIdx.x;
    if (gid >= N * 27) return;
    int n = gid / 27, k = gid - n * 27;
    int dx = k / 9, dy = (k / 3) % 3, dz = k % 3;
    int x = ipos[3 * n] - dx, y = ipos[3 * n + 1] - dy, z = ipos[3 * n + 2] - dz;
    if ((x | y | z) < 0) return;   // out coords must be >= 0
    int q = rtable[(x << 14) | (y << 7) | z];
    atomicAdd(&counts[q], 1);
}

__global__ void bases_k(int* __restrict__ counts, int* __restrict__ base,
                        int* __restrict__ total, int M) {
    int q = blockIdx.x * blockDim.x + threadIdx.x;
    if (q >= M) return;
    int c = counts[q];
    base[q] = atomicAdd(total, c);   // order-free segment assignment, no scan
    counts[q] = 0;                   // reuse as fill cursor
}

__global__ void fill_k(const int* __restrict__ ipos, const int* __restrict__ rtable,
                       const int* __restrict__ base, int* __restrict__ counts,
                       int* __restrict__ records, int N) {
    int gid = blockIdx.x * blockDim.x + threadIdx.x;
    if (gid >= N * 27) return;
    int n = gid / 27, k = gid - n * 27;
    int dx = k / 9, dy = (k / 3) % 3, dz = k % 3;
    int x = ipos[3 * n] - dx, y = ipos[3 * n + 1] - dy, z = ipos[3 * n + 2] - dz;
    if ((x | y | z) < 0) return;
    int q = rtable[(x << 14) | (y << 7) | z];
    int slot = base[q] + atomicAdd(&counts[q], 1);
    records[slot] = n | (k << 18);   // n < 2^18, k < 32
}

// 32 threads per output row; thread f computes out[q, f]. Exact hit list.
__global__ void gather_k(const int* __restrict__ base, const int* __restrict__ counts,
                         const int* __restrict__ records,
                         const float* __restrict__ feat, const float* __restrict__ W,
                         float* __restrict__ out, int M) {
    int gid = blockIdx.x * blockDim.x + threadIdx.x;
    int q = gid >> 5;
    int f = gid & 31;
    if (q >= M) return;
    int b = base[q], cnt = counts[q];
    float acc = 0.f;
    int rec = (cnt > 0) ? records[b] : 0;
    for (int r = 0; r < cnt; r++) {
        int nextrec = (r + 1 < cnt) ? records[b + r + 1] : 0;  // prefetch next record
        int n = rec & 0x3FFFF;
        int k = rec >> 18;
        const float4* fr = (const float4*)(feat + n * 32);
        const float* wk = W + k * 1024 + f;
        #pragma unroll
        for (int c = 0; c < 32; c += 4) {
            float4 x4 = fr[c >> 2];  // broadcast across the 32 lanes of this row
            acc += x4.x * wk[(c + 0) * 32];
            acc += x4.y * wk[(c + 1) * 32];
            acc += x4.z * wk[(c + 2) * 32];
            acc += x4.w * wk[(c + 3) * 32];
        }
        rec = nextrec;
    }
    out[q * 32 + f] = acc;
}

extern "C" void kernel_launch(void* const* d_in, const int* in_sizes, int n_in,
                              void* d_out, int out_size, void* d_ws, size_t ws_size,
                              hipStream_t stream) {
    const float* features = (const float*)d_in[0];
    const int* in_pos     = (const int*)d_in[1];
    const int* out_pos    = (const int*)d_in[2];
    const float* W        = (const float*)d_in[3];
    float* out            = (float*)d_out;

    const int N = in_sizes[1] / 3;
    const int M = in_sizes[2] / 3;

    char* p = (char*)d_ws;
    int* rtable  = (int*)p;  p += (size_t)CELLS * 4;
    int* counts  = (int*)p;  p += (size_t)M * 4;
    int* total   = (int*)p;  p += 4;
    int* base    = (int*)p;  p += (size_t)M * 4;
    int* records = (int*)p;

    hipMemsetAsync(counts, 0, (size_t)M * 4 + 4, stream);  // counts + total

    rtable_k<<<(M + 255) / 256, 256, 0, stream>>>(out_pos, rtable, M);
    count_k <<<(N * 27 + 255) / 256, 256, 0, stream>>>(in_pos, rtable, counts, N);
    bases_k <<<(M + 255) / 256, 256, 0, stream>>>(counts, base, total, M);
    fill_k  <<<(N * 27 + 255) / 256, 256, 0, stream>>>(in_pos, rtable, base, counts, records, N);
    gather_k<<<((size_t)M * 32 + 255) / 256, 256, 0, stream>>>(base, counts, records,
                                                               features, W, out, M);
}